// Round 4
// baseline (6447.481 us; speedup 1.0000x reference)
//
#include <hip/hip_runtime.h>
#include <stdint.h>

// LSTM B=64,T=512,I=512,H=512. out hs[T,B,H] fp32.
// 256 persistent wgs on 256 CUs:
//   wgs 0..127  = CONSUMERS: recurrence, h-part GEMM only (K=512), weights
//                 (w_hh) in registers as bf16 MFMA A-fragments, transposed-C
//                 so each lane's 4 acc regs = gates {i,f,g,o} of one
//                 (batch,col) -> lane-local cell update.
//   wgs 128..255 = PRODUCERS: xg[t] = x_t @ w_ih^T + (b_ih+b_hh) into a
//                 4-slot ring (d_ws, L3-resident), each value a relaxed
//                 agent-scope u64 [fp32 data | tag=t+1].
// h exchange: relaxed agent-scope u64 [2xbf16 | tag=t+1], double-buffered by
// parity. Consumers poll h-tags + xg-tags in one parallel-retry loop.
// Producers recycle slot t-4 after seeing h-tag >= t-3 from ALL 32 consumer
// wgs of their group. Out-stores batched 8 steps in registers (x8 unroll).

#define BATCH 64
#define TSTEPS 512
#define IDIM 512
#define HDIM 512
#define NGROUPS 4
#define BB 16
#define W_SLOTS 4
#define HB_U64 (BB * (HDIM / 2))                       // 4096 u64 / group / parity
#define H_TOTAL_U64 (2 * NGROUPS * HB_U64)             // 32768 u64 = 256KB
#define RING_U64 ((size_t)W_SLOTS * NGROUPS * 2048 * 16)  // 524288 u64 = 4MB

typedef __attribute__((ext_vector_type(4))) float f32x4;
typedef __attribute__((ext_vector_type(8))) short bf16x8;

__device__ inline unsigned short f2bf(float f) {
  unsigned u = __builtin_bit_cast(unsigned, f);
  u = (u + 0x7fffu + ((u >> 16) & 1u)) >> 16;  // RNE
  return (unsigned short)u;
}
__device__ inline float fast_sigmoid(float x) { return 1.f / (1.f + __expf(-x)); }
__device__ inline float fast_tanh(float x) { return 1.f - 2.f / (__expf(2.f * x) + 1.f); }

__global__ void lstm_init(uint64_t* __restrict__ buf) {
  // zero h_buf + ring tags (contiguous in ws); clears stale tags between
  // graph replays. tag 0 never matches any expected tag >= 1.
  const size_t n = (size_t)H_TOTAL_U64 + RING_U64;
  for (size_t j = (size_t)blockIdx.x * blockDim.x + threadIdx.x; j < n;
       j += (size_t)gridDim.x * blockDim.x)
    buf[j] = 0ull;
}

__global__ __launch_bounds__(256, 1)
void lstm_fused(const float* __restrict__ x,
                const float* __restrict__ w_ih,
                const float* __restrict__ w_hh,
                const float* __restrict__ b_ih,
                const float* __restrict__ b_hh,
                uint64_t* h_buf, uint64_t* ring,
                float* __restrict__ out) {
  __shared__ unsigned short S_lds[2][16 * 512];   // 32KB, XOR-swizzled rows

  const int tid = threadIdx.x;
  const int wave = tid >> 6;
  const int lane = tid & 63;
  const int hi4 = lane >> 4;
  const int nn = lane & 15;
  const int sm = tid >> 4;        // staging batch row
  const int sk = tid & 15;        // staging k-chunk
  const int wswz = (sm & 7) << 4;
  const int mrow = lane & 15;     // MFMA B-operand row = batch
  const int rswz = (mrow & 7) << 4;
  const int bi = lane & 15;       // this lane's batch row

  if (blockIdx.x >= 128) {
    // ============================ PRODUCER ============================
    const int p = blockIdx.x - 128;
    const int group = p >> 5;
    const int cb = (p & 31) * 16;                  // 16 h-cols per producer wg
    const int b0 = group * BB;
    // weight A-fragments from w_ih: tile-row nn -> gate=nn&3, colLocal=nn>>2
    const int growf = (nn & 3) * HDIM + cb + wave * 4 + (nn >> 2);
    bf16x8 breg[16];
#pragma unroll
    for (int kt = 0; kt < 16; ++kt) {
      const float* src = w_ih + (size_t)growf * IDIM + kt * 32 + hi4 * 8;
      bf16x8 v;
#pragma unroll
      for (int j = 0; j < 8; ++j) v[j] = (short)f2bf(src[j]);
      breg[kt] = v;
    }
    const int mycolp = cb + wave * 4 + hi4;
    float bv[4];
#pragma unroll
    for (int r = 0; r < 4; ++r)
      bv[r] = b_ih[r * HDIM + mycolp] + b_hh[r * HDIM + mycolp];

    for (int t = 0; t < TSTEPS; ++t) {
      const int cur = t & 1;
      // stage x_t -> S_lds[cur]
      const float* xp = x + ((size_t)(b0 + sm) * TSTEPS + t) * IDIM + sk * 32;
#pragma unroll
      for (int q = 0; q < 4; ++q) {
        float4 fa = *(const float4*)(xp + q * 8);
        float4 fb = *(const float4*)(xp + q * 8 + 4);
        bf16x8 v;
        v[0] = (short)f2bf(fa.x); v[1] = (short)f2bf(fa.y);
        v[2] = (short)f2bf(fa.z); v[3] = (short)f2bf(fa.w);
        v[4] = (short)f2bf(fb.x); v[5] = (short)f2bf(fb.y);
        v[6] = (short)f2bf(fb.z); v[7] = (short)f2bf(fb.w);
        *(bf16x8*)((char*)&S_lds[cur][0] + ((sm * 1024 + (sk * 4 + q) * 16) ^ wswz)) = v;
      }
      __syncthreads();
      f32x4 acc0 = {0.f, 0.f, 0.f, 0.f}, acc1 = {0.f, 0.f, 0.f, 0.f};
#pragma unroll
      for (int kt = 0; kt < 16; kt += 2) {
        bf16x8 a0 = *(const bf16x8*)((const char*)&S_lds[cur][0] +
                      ((mrow * 1024 + (kt * 4 + hi4) * 16) ^ rswz));
        acc0 = __builtin_amdgcn_mfma_f32_16x16x32_bf16(breg[kt], a0, acc0, 0, 0, 0);
        bf16x8 a1 = *(const bf16x8*)((const char*)&S_lds[cur][0] +
                      ((mrow * 1024 + ((kt + 1) * 4 + hi4) * 16) ^ rswz));
        acc1 = __builtin_amdgcn_mfma_f32_16x16x32_bf16(breg[kt + 1], a1, acc1, 0, 0, 0);
      }
      // slot reuse: wait until ALL 32 consumer wgs passed step t-4
      // (each published h tag >= t-3; thread tid checks wg (tid&31)'s word)
      if (t >= W_SLOTS) {
        const uint32_t tgt = (uint32_t)(t - W_SLOTS + 1);
        const uint64_t* hw = h_buf + ((size_t)(tgt & 1) * NGROUPS + group) * HB_U64
                           + (size_t)(tid & 31) * 8;
        while ((uint32_t)__hip_atomic_load(hw, __ATOMIC_RELAXED,
                                           __HIP_MEMORY_SCOPE_AGENT) < tgt)
          __builtin_amdgcn_s_sleep(1);
      }
      // publish xg tile: tag = t+1
      uint64_t* rp = ring + ((size_t)(t & (W_SLOTS - 1)) * NGROUPS + group) * (2048 * 16);
#pragma unroll
      for (int r = 0; r < 4; ++r) {
        const float gv = acc0[r] + acc1[r] + bv[r];
        const uint64_t val = (uint64_t)(uint32_t)(t + 1)
                           | ((uint64_t)__builtin_bit_cast(uint32_t, gv) << 32);
        __hip_atomic_store(rp + (size_t)(r * HDIM + mycolp) * 16 + bi, val,
                           __ATOMIC_RELAXED, __HIP_MEMORY_SCOPE_AGENT);
      }
    }
  } else {
    // ============================ CONSUMER ============================
    const int group = blockIdx.x >> 5;
    const int h0 = (blockIdx.x & 31) * 16;
    const int b0 = group * BB;
    // weight A-fragments from w_hh (K = HDIM)
    const int growf = (nn & 3) * HDIM + h0 + wave * 4 + (nn >> 2);
    bf16x8 breg[16];
#pragma unroll
    for (int kt = 0; kt < 16; ++kt) {
      const float* src = w_hh + (size_t)growf * HDIM + kt * 32 + hi4 * 8;
      bf16x8 v;
#pragma unroll
      for (int j = 0; j < 8; ++j) v[j] = (short)f2bf(src[j]);
      breg[kt] = v;
    }
    const int mycol = h0 + wave * 4 + hi4;
    const size_t obase = (size_t)(b0 + bi) * HDIM + mycol;
    float c = 0.f;
    float hout[8];

    for (int tb = 0; tb < TSTEPS; tb += 8) {
#pragma unroll
      for (int u = 0; u < 8; ++u) {
        const int t = tb + u;
        const int cur = t & 1;
        // ---- combined poll: h (16 u64) + xg (4 u64), parallel retry ----
        uint64_t hu[16], xgv[4];
        const uint64_t* hp = h_buf + ((size_t)cur * NGROUPS + group) * HB_U64
                           + (size_t)sm * (HDIM / 2) + sk * 16;
        const uint64_t* rp = ring + ((size_t)(t & (W_SLOTS - 1)) * NGROUPS + group) * (2048 * 16);
        if (t > 0) {
#pragma unroll
          for (int j = 0; j < 16; ++j)
            hu[j] = __hip_atomic_load(hp + j, __ATOMIC_RELAXED, __HIP_MEMORY_SCOPE_AGENT);
        }
#pragma unroll
        for (int r = 0; r < 4; ++r)
          xgv[r] = __hip_atomic_load(rp + (size_t)(r * HDIM + mycol) * 16 + bi,
                                     __ATOMIC_RELAXED, __HIP_MEMORY_SCOPE_AGENT);
        while (true) {
          bool ok = true;
          if (t > 0) {
#pragma unroll
            for (int j = 0; j < 16; ++j) ok &= ((uint32_t)hu[j] == (uint32_t)t);
          }
#pragma unroll
          for (int r = 0; r < 4; ++r) ok &= ((uint32_t)xgv[r] == (uint32_t)(t + 1));
          if (ok) break;
          if (t > 0) {
#pragma unroll
            for (int j = 0; j < 16; ++j)
              hu[j] = __hip_atomic_load(hp + j, __ATOMIC_RELAXED, __HIP_MEMORY_SCOPE_AGENT);
          }
#pragma unroll
          for (int r = 0; r < 4; ++r)
            xgv[r] = __hip_atomic_load(rp + (size_t)(r * HDIM + mycol) * 16 + bi,
                                       __ATOMIC_RELAXED, __HIP_MEMORY_SCOPE_AGENT);
        }
        // ---- stage h, barrier, 16 h-part MFMAs ----
        f32x4 acc0 = {0.f, 0.f, 0.f, 0.f}, acc1 = {0.f, 0.f, 0.f, 0.f};
        if (t > 0) {
#pragma unroll
          for (int q = 0; q < 4; ++q) {
            bf16x8 v;
#pragma unroll
            for (int jj = 0; jj < 4; ++jj) {
              const uint32_t d = (uint32_t)(hu[q * 4 + jj] >> 32);
              v[jj * 2] = (short)(d & 0xffffu);
              v[jj * 2 + 1] = (short)(d >> 16);
            }
            *(bf16x8*)((char*)&S_lds[cur][0] + ((sm * 1024 + (sk * 4 + q) * 16) ^ wswz)) = v;
          }
          __syncthreads();
#pragma unroll
          for (int kt = 0; kt < 16; kt += 2) {
            bf16x8 a0 = *(const bf16x8*)((const char*)&S_lds[cur][0] +
                          ((mrow * 1024 + (kt * 4 + hi4) * 16) ^ rswz));
            acc0 = __builtin_amdgcn_mfma_f32_16x16x32_bf16(breg[kt], a0, acc0, 0, 0, 0);
            bf16x8 a1 = *(const bf16x8*)((const char*)&S_lds[cur][0] +
                          ((mrow * 1024 + ((kt + 1) * 4 + hi4) * 16) ^ rswz));
            acc1 = __builtin_amdgcn_mfma_f32_16x16x32_bf16(breg[kt + 1], a1, acc1, 0, 0, 0);
          }
        }
        // ---- lane-local gates: acc regs 0..3 = i,f,g,o + fp32 xg ----
        const float gi = acc0[0] + acc1[0] + __builtin_bit_cast(float, (uint32_t)(xgv[0] >> 32));
        const float gf = acc0[1] + acc1[1] + __builtin_bit_cast(float, (uint32_t)(xgv[1] >> 32));
        const float gg = acc0[2] + acc1[2] + __builtin_bit_cast(float, (uint32_t)(xgv[2] >> 32));
        const float go = acc0[3] + acc1[3] + __builtin_bit_cast(float, (uint32_t)(xgv[3] >> 32));
        c = fast_sigmoid(gf) * c + fast_sigmoid(gi) * fast_tanh(gg);
        const float hval = fast_sigmoid(go) * fast_tanh(c);
        // ---- publish h_{t+1} (tag t+1) immediately ----
        if (t + 1 < TSTEPS) {
          const unsigned hb = (unsigned)f2bf(hval);
          const unsigned pb = (unsigned)__shfl_xor((int)hb, 16, 64);
          if ((hi4 & 1) == 0) {
            const uint64_t val = (uint64_t)(uint32_t)(t + 1)
                               | ((uint64_t)(hb | (pb << 16)) << 32);
            __hip_atomic_store(h_buf + ((size_t)((t + 1) & 1) * NGROUPS + group) * HB_U64
                                 + (size_t)bi * (HDIM / 2) + (mycol >> 1),
                               val, __ATOMIC_RELAXED, __HIP_MEMORY_SCOPE_AGENT);
          }
        }
        hout[u] = hval;   // static index (unrolled) -> stays in VGPRs
      }
      // ---- batched out flush (off the per-step critical path) ----
#pragma unroll
      for (int k = 0; k < 8; ++k)
        out[(size_t)(tb + k) * (BATCH * HDIM) + obase] = hout[k];
    }
  }
}

extern "C" void kernel_launch(void* const* d_in, const int* in_sizes, int n_in,
                              void* d_out, int out_size, void* d_ws, size_t ws_size,
                              hipStream_t stream) {
  const float* x    = (const float*)d_in[0];
  const float* w_ih = (const float*)d_in[1];
  const float* w_hh = (const float*)d_in[2];
  const float* b_ih = (const float*)d_in[3];
  const float* b_hh = (const float*)d_in[4];
  float* out = (float*)d_out;

  uint64_t* h_buf = (uint64_t*)d_ws;                 // 256KB
  uint64_t* ring  = h_buf + H_TOTAL_U64;             // 4MB

  lstm_init<<<256, 256, 0, stream>>>(h_buf);
  lstm_fused<<<256, 256, 0, stream>>>(x, w_ih, w_hh, b_ih, b_hh, h_buf, ring, out);
}

// Round 5
// 5223.180 us; speedup vs baseline: 1.2344x; 1.2344x over previous
//
#include <hip/hip_runtime.h>
#include <stdint.h>

// LSTM B=64,T=512,I=512,H=512. out hs[T,B,H] fp32.
// Persistent: 4 batch-groups x 32 wgs (128 wgs, 256 thr). Each wg: 16 batch
// rows x 16 h-cols (all 4 gates). Weights (K=1024 = [w_ih|w_hh]) in registers
// as bf16 MFMA fragments, transposed-C: acc = mfma(W_frag, A_frag) so each
// lane's 4 acc regs = gates {i,f,g,o} of one (batch,col) -> lane-local cell.
// Per step: issue h-tag poll loads, x-part MFMAs overlap the poll flight,
// parallel-retry poll, stage h + x_{t+1}, ONE __syncthreads, h-part MFMAs,
// elementwise, publish tagged h (relaxed agent u64 [2xbf16|tag]).
// R5 fixes vs R3: (1) x_{t+2} loads issued AFTER the poll region (xfA/xfB
// ping-pong, sched_barrier-pinned) so poll vmcnt(0) never waits HBM x;
// (2) out stores batched 8 steps in registers.

#define BATCH 64
#define TSTEPS 512
#define IDIM 512
#define HDIM 512
#define WGS_PER_GROUP 32
#define NGROUPS 4
#define BB 16
#define NWG (WGS_PER_GROUP * NGROUPS)
#define HB_U64_PER_GROUP (BB * (HDIM / 2))   // 4096 u64 per buffer per group

typedef __attribute__((ext_vector_type(4))) float f32x4;
typedef __attribute__((ext_vector_type(8))) short bf16x8;

__device__ inline unsigned short f2bf(float f) {
  unsigned u = __builtin_bit_cast(unsigned, f);
  u = (u + 0x7fffu + ((u >> 16) & 1u)) >> 16;  // RNE
  return (unsigned short)u;
}
__device__ inline float fast_sigmoid(float x) { return 1.f / (1.f + __expf(-x)); }
__device__ inline float fast_tanh(float x) { return 1.f - 2.f / (__expf(2.f * x) + 1.f); }

__global__ void lstm_init(const float* __restrict__ b_ih, const float* __restrict__ b_hh,
                          float* __restrict__ bias, uint64_t* __restrict__ h_buf) {
  const int i = blockIdx.x * blockDim.x + threadIdx.x;
  if (i < 4 * HDIM) bias[i] = b_ih[i] + b_hh[i];
  // zero both tagged-h buffers (tag 0 never matches expected tag >= 1;
  // clears stale tags between graph replays)
  for (int j = i; j < 2 * NGROUPS * HB_U64_PER_GROUP; j += 2048) h_buf[j] = 0ull;
}

__global__ __launch_bounds__(256, 1)
void lstm_persistent(const float* __restrict__ x,
                     const float* __restrict__ w_ih,
                     const float* __restrict__ w_hh,
                     const float* __restrict__ bias,
                     uint64_t* h_buf,   // [2][NGROUPS][BB][HDIM/2] tagged pairs
                     float* __restrict__ out) {
  __shared__ unsigned short X_lds[2][16 * IDIM];   // 2 x 16KB, XOR-swizzled
  __shared__ unsigned short H_lds[2][16 * HDIM];   // 2 x 16KB, XOR-swizzled

  const int wg = blockIdx.x;
  const int group = wg >> 5;
  const int wgg = wg & 31;
  const int b0 = group * BB;
  const int h0 = wgg * 16;
  const int tid = threadIdx.x;
  const int wave = tid >> 6;
  const int lane = tid & 63;
  const int hi4 = lane >> 4;

  // ---- one-time: weight A-fragments (transposed-C form) ----
  const int nn = lane & 15;
  const int growf = (nn & 3) * HDIM + h0 + wave * 4 + (nn >> 2);  // gate row
  bf16x8 breg[32];
#pragma unroll
  for (int kt = 0; kt < 32; ++kt) {
    const int k = kt * 32 + hi4 * 8;
    const float* src = (k < IDIM) ? (w_ih + (size_t)growf * IDIM + k)
                                  : (w_hh + (size_t)growf * HDIM + (k - IDIM));
    bf16x8 v;
#pragma unroll
    for (int j = 0; j < 8; ++j) v[j] = (short)f2bf(src[j]);
    breg[kt] = v;
  }
  const int mycol = h0 + wave * 4 + hi4;   // this lane's h column
  const float bv0 = bias[0 * HDIM + mycol];
  const float bv1 = bias[1 * HDIM + mycol];
  const float bv2 = bias[2 * HDIM + mycol];
  const float bv3 = bias[3 * HDIM + mycol];

  // staging roles
  const int sm = tid >> 4;   // batch row 0..15
  const int sk = tid & 15;   // k-chunk of 32
  const int wswz = (sm & 7) << 4;
  const int mrow = lane & 15;             // MFMA B-operand row = batch
  const int rswz = (mrow & 7) << 4;
  const int bi = lane & 15;

  // ---- prologue: stage x_0 -> X_lds[0]; preload xfA = x_1 ----
  {
    const float* xp = x + ((size_t)(b0 + sm) * TSTEPS + 0) * IDIM + sk * 32;
#pragma unroll
    for (int q = 0; q < 4; ++q) {
      float4 fa = *(const float4*)(xp + q * 8);
      float4 fb = *(const float4*)(xp + q * 8 + 4);
      bf16x8 v;
      v[0] = (short)f2bf(fa.x); v[1] = (short)f2bf(fa.y);
      v[2] = (short)f2bf(fa.z); v[3] = (short)f2bf(fa.w);
      v[4] = (short)f2bf(fb.x); v[5] = (short)f2bf(fb.y);
      v[6] = (short)f2bf(fb.z); v[7] = (short)f2bf(fb.w);
      *(bf16x8*)((char*)&X_lds[0][0] + ((sm * 1024 + (sk * 4 + q) * 16) ^ wswz)) = v;
    }
  }
  float4 xfA[8], xfB[8];
  {
    const float* xp = x + ((size_t)(b0 + sm) * TSTEPS + 1) * IDIM + sk * 32;
#pragma unroll
    for (int q = 0; q < 8; ++q) xfA[q] = *(const float4*)(xp + q * 4);
  }
  __syncthreads();

  float c = 0.f;   // cell state for (batch=lane&15, col=mycol)
  float hout[8];
  const size_t obase = (size_t)(b0 + bi) * HDIM + mycol;

  for (int tb = 0; tb < TSTEPS; tb += 8) {
#pragma unroll
    for (int u = 0; u < 8; ++u) {
      const int t = tb + u;
      const int cur = t & 1;

      // ---- issue h_t tag poll loads ----
      uint64_t hu[16];
      const uint64_t* hp = h_buf + ((size_t)cur * NGROUPS + group) * HB_U64_PER_GROUP
                         + (size_t)sm * (HDIM / 2) + sk * 16;
      if (t > 0) {
#pragma unroll
        for (int j = 0; j < 16; ++j)
          hu[j] = __hip_atomic_load(hp + j, __ATOMIC_RELAXED, __HIP_MEMORY_SCOPE_AGENT);
      }

      // ---- phase A: x-part MFMAs (kt 0..15) overlap the poll flight ----
      f32x4 acc0 = {0.f, 0.f, 0.f, 0.f}, acc1 = {0.f, 0.f, 0.f, 0.f};
#pragma unroll
      for (int kt = 0; kt < 16; kt += 2) {
        bf16x8 a0 = *(const bf16x8*)((const char*)&X_lds[cur][0] +
                      ((mrow * 1024 + (kt * 4 + hi4) * 16) ^ rswz));
        acc0 = __builtin_amdgcn_mfma_f32_16x16x32_bf16(breg[kt], a0, acc0, 0, 0, 0);
        bf16x8 a1 = *(const bf16x8*)((const char*)&X_lds[cur][0] +
                      ((mrow * 1024 + ((kt + 1) * 4 + hi4) * 16) ^ rswz));
        acc1 = __builtin_amdgcn_mfma_f32_16x16x32_bf16(breg[kt + 1], a1, acc1, 0, 0, 0);
      }

      // ---- poll check (parallel retry: reload ALL 16 per round) ----
      if (t > 0) {
        while (true) {
          bool ok = true;
#pragma unroll
          for (int j = 0; j < 16; ++j) ok &= ((uint32_t)hu[j] == (uint32_t)t);
          if (ok) break;
#pragma unroll
          for (int j = 0; j < 16; ++j)
            hu[j] = __hip_atomic_load(hp + j, __ATOMIC_RELAXED, __HIP_MEMORY_SCOPE_AGENT);
        }
      }

      // ---- x_{t+2} prefetch issue (pinned AFTER the poll region) ----
      __builtin_amdgcn_sched_barrier(0);
      if (t + 2 < TSTEPS) {
        const float* xp = x + ((size_t)(b0 + sm) * TSTEPS + (t + 2)) * IDIM + sk * 32;
        if ((u & 1) == 0) {
#pragma unroll
          for (int q = 0; q < 8; ++q) xfB[q] = *(const float4*)(xp + q * 4);
        } else {
#pragma unroll
          for (int q = 0; q < 8; ++q) xfA[q] = *(const float4*)(xp + q * 4);
        }
      }
      __builtin_amdgcn_sched_barrier(0);

      // ---- phase B: stage h -> H_lds[cur]; stage x_{t+1} -> X_lds[cur^1] ----
      if (t > 0) {
#pragma unroll
        for (int q = 0; q < 4; ++q) {
          bf16x8 v;
#pragma unroll
          for (int jj = 0; jj < 4; ++jj) {
            const uint32_t d = (uint32_t)(hu[q * 4 + jj] >> 32);
            v[jj * 2] = (short)(d & 0xffffu);
            v[jj * 2 + 1] = (short)(d >> 16);
          }
          *(bf16x8*)((char*)&H_lds[cur][0] + ((sm * 1024 + (sk * 4 + q) * 16) ^ wswz)) = v;
        }
      }
      if (t + 1 < TSTEPS) {
#pragma unroll
        for (int q = 0; q < 4; ++q) {
          float4 fa, fb;
          if ((u & 1) == 0) { fa = xfA[q * 2]; fb = xfA[q * 2 + 1]; }
          else              { fa = xfB[q * 2]; fb = xfB[q * 2 + 1]; }
          bf16x8 v;
          v[0] = (short)f2bf(fa.x); v[1] = (short)f2bf(fa.y);
          v[2] = (short)f2bf(fa.z); v[3] = (short)f2bf(fa.w);
          v[4] = (short)f2bf(fb.x); v[5] = (short)f2bf(fb.y);
          v[6] = (short)f2bf(fb.z); v[7] = (short)f2bf(fb.w);
          *(bf16x8*)((char*)&X_lds[cur ^ 1][0] + ((sm * 1024 + (sk * 4 + q) * 16) ^ wswz)) = v;
        }
      }
      __syncthreads();   // the ONLY barrier per step

      // ---- phase C: h-part MFMAs (kt 16..31) ----
      if (t > 0) {
#pragma unroll
        for (int kt = 0; kt < 16; kt += 2) {
          bf16x8 a0 = *(const bf16x8*)((const char*)&H_lds[cur][0] +
                        ((mrow * 1024 + (kt * 4 + hi4) * 16) ^ rswz));
          acc0 = __builtin_amdgcn_mfma_f32_16x16x32_bf16(breg[16 + kt], a0, acc0, 0, 0, 0);
          bf16x8 a1 = *(const bf16x8*)((const char*)&H_lds[cur][0] +
                        ((mrow * 1024 + ((kt + 1) * 4 + hi4) * 16) ^ rswz));
          acc1 = __builtin_amdgcn_mfma_f32_16x16x32_bf16(breg[17 + kt], a1, acc1, 0, 0, 0);
        }
      }

      // ---- elementwise: lane-local gates i,f,g,o in acc regs 0..3 ----
      const float gi = acc0[0] + acc1[0] + bv0;
      const float gf = acc0[1] + acc1[1] + bv1;
      const float gg = acc0[2] + acc1[2] + bv2;
      const float go = acc0[3] + acc1[3] + bv3;
      c = fast_sigmoid(gf) * c + fast_sigmoid(gi) * fast_tanh(gg);
      const float hval = fast_sigmoid(go) * fast_tanh(c);

      // ---- publish h_{t+1} (tag t+1) immediately ----
      if (t + 1 < TSTEPS) {
        const unsigned hb = (unsigned)f2bf(hval);
        const unsigned pb = (unsigned)__shfl_xor((int)hb, 16, 64);
        if ((hi4 & 1) == 0) {
          const uint64_t val = (uint64_t)(uint32_t)(t + 1)
                             | ((uint64_t)(hb | (pb << 16)) << 32);
          __hip_atomic_store(h_buf + ((size_t)((t + 1) & 1) * NGROUPS + group) * HB_U64_PER_GROUP
                               + (size_t)bi * (HDIM / 2) + (mycol >> 1),
                             val, __ATOMIC_RELAXED, __HIP_MEMORY_SCOPE_AGENT);
        }
      }
      hout[u] = hval;   // static index (unrolled) -> stays in VGPRs
    }
    // ---- batched out flush (couples into a poll only once per 8 steps) ----
#pragma unroll
    for (int k = 0; k < 8; ++k)
      out[(size_t)(tb + k) * (BATCH * HDIM) + obase] = hout[k];
  }
}

extern "C" void kernel_launch(void* const* d_in, const int* in_sizes, int n_in,
                              void* d_out, int out_size, void* d_ws, size_t ws_size,
                              hipStream_t stream) {
  const float* x    = (const float*)d_in[0];
  const float* w_ih = (const float*)d_in[1];
  const float* w_hh = (const float*)d_in[2];
  const float* b_ih = (const float*)d_in[3];
  const float* b_hh = (const float*)d_in[4];
  float* out = (float*)d_out;

  char* ws = (char*)d_ws;
  float* bias = (float*)ws;                          // 8KB
  uint64_t* h_buf = (uint64_t*)(ws + 8192);          // 256KB tagged pairs

  lstm_init<<<8, 256, 0, stream>>>(b_ih, b_hh, bias, h_buf);
  lstm_persistent<<<NWG, 256, 0, stream>>>(x, w_ih, w_hh, bias, h_buf, out);
}

// Round 7
// 2618.251 us; speedup vs baseline: 2.4625x; 1.9949x over previous
//
#include <hip/hip_runtime.h>
#include <stdint.h>

// LSTM B=64,T=512,I=512,H=512. out hs[T,B,H] fp32.
// Persistent: 4 batch-groups x 32 wgs (128 wgs, 256 thr). Each wg: 16 batch
// rows x 16 h-cols (all 4 gates). Weights (K=1024 = [w_ih|w_hh]) in registers
// as bf16 MFMA fragments, transposed-C: acc = mfma(W_frag, A_frag) so each
// lane's 4 acc regs = gates {i,f,g,o} of one (batch,col) -> lane-local cell.
// Per step: COALESCED poll (thread (w,l) loads u64 g = w*1024+j*64+l: each
// load instr = 64 consecutive u64 = 512B, minimal transactions), x-part
// MFMAs overlap poll flight, parallel retry, restage h to LDS (1024B rows!),
// stage x_{t+1}, ONE barrier, h-part MFMAs, elementwise, publish tagged h
// (relaxed agent u64 [2xbf16|tag]). x_{t+2} prefetch issued AFTER the
// barrier (never drained by it). out stores batched 8 steps in registers.
// R7 fix vs R6: restage row stride 2048 -> 1024 (H_lds rows are 512 bf16 =
// 1024 B; the 2048 stride wrote past the buffer -> NaN).

#define BATCH 64
#define TSTEPS 512
#define IDIM 512
#define HDIM 512
#define WGS_PER_GROUP 32
#define NGROUPS 4
#define BB 16
#define NWG (WGS_PER_GROUP * NGROUPS)
#define HB_U64_PER_GROUP (BB * (HDIM / 2))   // 4096 u64 per buffer per group

typedef __attribute__((ext_vector_type(4))) float f32x4;
typedef __attribute__((ext_vector_type(8))) short bf16x8;

__device__ inline unsigned short f2bf(float f) {
  unsigned u = __builtin_bit_cast(unsigned, f);
  u = (u + 0x7fffu + ((u >> 16) & 1u)) >> 16;  // RNE
  return (unsigned short)u;
}
__device__ inline float fast_sigmoid(float x) { return 1.f / (1.f + __expf(-x)); }
__device__ inline float fast_tanh(float x) { return 1.f - 2.f / (__expf(2.f * x) + 1.f); }

__global__ void lstm_init(const float* __restrict__ b_ih, const float* __restrict__ b_hh,
                          float* __restrict__ bias, uint64_t* __restrict__ h_buf) {
  const int i = blockIdx.x * blockDim.x + threadIdx.x;
  if (i < 4 * HDIM) bias[i] = b_ih[i] + b_hh[i];
  // zero both tagged-h buffers (tag 0 never matches expected tag >= 1;
  // clears stale tags between graph replays)
  for (int j = i; j < 2 * NGROUPS * HB_U64_PER_GROUP; j += 2048) h_buf[j] = 0ull;
}

__global__ __launch_bounds__(256, 1)
void lstm_persistent(const float* __restrict__ x,
                     const float* __restrict__ w_ih,
                     const float* __restrict__ w_hh,
                     const float* __restrict__ bias,
                     uint64_t* h_buf,   // [2][NGROUPS][BB][HDIM/2] tagged pairs
                     float* __restrict__ out) {
  __shared__ unsigned short X_lds[2][16 * IDIM];   // 2 x 16KB, XOR-swizzled
  __shared__ unsigned short H_lds[2][16 * HDIM];   // 2 x 16KB, XOR-swizzled

  const int wg = blockIdx.x;
  const int group = wg >> 5;
  const int wgg = wg & 31;
  const int b0 = group * BB;
  const int h0 = wgg * 16;
  const int tid = threadIdx.x;
  const int wave = tid >> 6;
  const int lane = tid & 63;
  const int hi4 = lane >> 4;

  // ---- one-time: weight A-fragments (transposed-C form) ----
  const int nn = lane & 15;
  const int growf = (nn & 3) * HDIM + h0 + wave * 4 + (nn >> 2);  // gate row
  bf16x8 breg[32];
#pragma unroll
  for (int kt = 0; kt < 32; ++kt) {
    const int k = kt * 32 + hi4 * 8;
    const float* src = (k < IDIM) ? (w_ih + (size_t)growf * IDIM + k)
                                  : (w_hh + (size_t)growf * HDIM + (k - IDIM));
    bf16x8 v;
#pragma unroll
    for (int j = 0; j < 8; ++j) v[j] = (short)f2bf(src[j]);
    breg[kt] = v;
  }
  const int mycol = h0 + wave * 4 + hi4;   // this lane's h column
  const float bv0 = bias[0 * HDIM + mycol];
  const float bv1 = bias[1 * HDIM + mycol];
  const float bv2 = bias[2 * HDIM + mycol];
  const float bv3 = bias[3 * HDIM + mycol];

  // staging roles (x): thread -> (batch row sm, k-chunk sk)
  const int sm = tid >> 4;
  const int sk = tid & 15;
  const int wswz = (sm & 7) << 4;
  const int mrow = lane & 15;             // MFMA B-operand row = batch
  const int rswz = (mrow & 7) << 4;
  const int bi = lane & 15;

  // ---- prologue: stage x_0 -> X_lds[0]; preload xfA = x_1 ----
  {
    const float* xp = x + ((size_t)(b0 + sm) * TSTEPS + 0) * IDIM + sk * 32;
#pragma unroll
    for (int q = 0; q < 4; ++q) {
      float4 fa = *(const float4*)(xp + q * 8);
      float4 fb = *(const float4*)(xp + q * 8 + 4);
      bf16x8 v;
      v[0] = (short)f2bf(fa.x); v[1] = (short)f2bf(fa.y);
      v[2] = (short)f2bf(fa.z); v[3] = (short)f2bf(fa.w);
      v[4] = (short)f2bf(fb.x); v[5] = (short)f2bf(fb.y);
      v[6] = (short)f2bf(fb.z); v[7] = (short)f2bf(fb.w);
      *(bf16x8*)((char*)&X_lds[0][0] + ((sm * 1024 + (sk * 4 + q) * 16) ^ wswz)) = v;
    }
  }
  float4 xfA[8], xfB[8];
  {
    const float* xp = x + ((size_t)(b0 + sm) * TSTEPS + 1) * IDIM + sk * 32;
#pragma unroll
    for (int q = 0; q < 8; ++q) xfA[q] = *(const float4*)(xp + q * 4);
  }
  __syncthreads();

  float c = 0.f;   // cell state for (batch=lane&15, col=mycol)
  float hout[8];
  const size_t obase = (size_t)(b0 + bi) * HDIM + mycol;

  for (int tb = 0; tb < TSTEPS; tb += 8) {
#pragma unroll
    for (int u = 0; u < 8; ++u) {
      const int t = tb + u;
      const int cur = t & 1;

      // ---- issue h_t poll loads, COALESCED: u64 g = wave*1024 + j*64 + lane
      // (each load instr: 64 consecutive u64 = 512B) ----
      uint64_t hu[16];
      const uint64_t* hpb = h_buf + ((size_t)cur * NGROUPS + group) * HB_U64_PER_GROUP
                          + (size_t)wave * 1024 + lane;
      if (t > 0) {
#pragma unroll
        for (int j = 0; j < 16; ++j)
          hu[j] = __hip_atomic_load(hpb + j * 64, __ATOMIC_RELAXED, __HIP_MEMORY_SCOPE_AGENT);
      }

      // ---- phase A: x-part MFMAs (kt 0..15) overlap the poll flight ----
      f32x4 acc0 = {0.f, 0.f, 0.f, 0.f}, acc1 = {0.f, 0.f, 0.f, 0.f};
#pragma unroll
      for (int kt = 0; kt < 16; kt += 2) {
        bf16x8 a0 = *(const bf16x8*)((const char*)&X_lds[cur][0] +
                      ((mrow * 1024 + (kt * 4 + hi4) * 16) ^ rswz));
        acc0 = __builtin_amdgcn_mfma_f32_16x16x32_bf16(breg[kt], a0, acc0, 0, 0, 0);
        bf16x8 a1 = *(const bf16x8*)((const char*)&X_lds[cur][0] +
                      ((mrow * 1024 + ((kt + 1) * 4 + hi4) * 16) ^ rswz));
        acc1 = __builtin_amdgcn_mfma_f32_16x16x32_bf16(breg[kt + 1], a1, acc1, 0, 0, 0);
      }

      // ---- poll check (parallel retry: reload ALL 16 per round) ----
      if (t > 0) {
        while (true) {
          bool ok = true;
#pragma unroll
          for (int j = 0; j < 16; ++j) ok &= ((uint32_t)hu[j] == (uint32_t)t);
          if (ok) break;
#pragma unroll
          for (int j = 0; j < 16; ++j)
            hu[j] = __hip_atomic_load(hpb + j * 64, __ATOMIC_RELAXED, __HIP_MEMORY_SCOPE_AGENT);
        }
        // ---- restage h -> H_lds[cur]: word g = wave*1024+j*64+lane decomposes
        // bi_ = wave*4+(j>>2), colpair cp = (j&3)*64+lane; u32 pair cp lives at
        // byte cp*4 of the 1024-B row; swizzle matches read side (bits 4..6).
        // Per instr lanes write consecutive 4B -> conflict-free. ----
#pragma unroll
        for (int j = 0; j < 16; ++j) {
          const int bi_ = wave * 4 + (j >> 2);
          const int byte = (bi_ * 1024 + ((j & 3) * 64 + lane) * 4) ^ ((bi_ & 7) << 4);
          *(uint32_t*)((char*)&H_lds[cur][0] + byte) = (uint32_t)(hu[j] >> 32);
        }
      }

      // ---- stage x_{t+1} -> X_lds[cur^1] from the reg bank loaded last step ----
      if (t + 1 < TSTEPS) {
#pragma unroll
        for (int q = 0; q < 4; ++q) {
          float4 fa, fb;
          if ((u & 1) == 0) { fa = xfA[q * 2]; fb = xfA[q * 2 + 1]; }
          else              { fa = xfB[q * 2]; fb = xfB[q * 2 + 1]; }
          bf16x8 v;
          v[0] = (short)f2bf(fa.x); v[1] = (short)f2bf(fa.y);
          v[2] = (short)f2bf(fa.z); v[3] = (short)f2bf(fa.w);
          v[4] = (short)f2bf(fb.x); v[5] = (short)f2bf(fb.y);
          v[6] = (short)f2bf(fb.z); v[7] = (short)f2bf(fb.w);
          *(bf16x8*)((char*)&X_lds[cur ^ 1][0] + ((sm * 1024 + (sk * 4 + q) * 16) ^ wswz)) = v;
        }
      }
      __syncthreads();   // the ONLY barrier per step (no fresh vmem before it)

      // ---- x_{t+2} prefetch issue: AFTER the barrier, ~1-2us of flight ----
      if (t + 2 < TSTEPS) {
        const float* xp = x + ((size_t)(b0 + sm) * TSTEPS + (t + 2)) * IDIM + sk * 32;
        if ((u & 1) == 0) {
#pragma unroll
          for (int q = 0; q < 8; ++q) xfB[q] = *(const float4*)(xp + q * 4);
        } else {
#pragma unroll
          for (int q = 0; q < 8; ++q) xfA[q] = *(const float4*)(xp + q * 4);
        }
      }
      __builtin_amdgcn_sched_barrier(0);

      // ---- phase C: h-part MFMAs (kt 16..31) ----
      if (t > 0) {
#pragma unroll
        for (int kt = 0; kt < 16; kt += 2) {
          bf16x8 a0 = *(const bf16x8*)((const char*)&H_lds[cur][0] +
                        ((mrow * 1024 + (kt * 4 + hi4) * 16) ^ rswz));
          acc0 = __builtin_amdgcn_mfma_f32_16x16x32_bf16(breg[16 + kt], a0, acc0, 0, 0, 0);
          bf16x8 a1 = *(const bf16x8*)((const char*)&H_lds[cur][0] +
                        ((mrow * 1024 + ((kt + 1) * 4 + hi4) * 16) ^ rswz));
          acc1 = __builtin_amdgcn_mfma_f32_16x16x32_bf16(breg[17 + kt], a1, acc1, 0, 0, 0);
        }
      }

      // ---- elementwise: lane-local gates i,f,g,o in acc regs 0..3 ----
      const float gi = acc0[0] + acc1[0] + bv0;
      const float gf = acc0[1] + acc1[1] + bv1;
      const float gg = acc0[2] + acc1[2] + bv2;
      const float go = acc0[3] + acc1[3] + bv3;
      c = fast_sigmoid(gf) * c + fast_sigmoid(gi) * fast_tanh(gg);
      const float hval = fast_sigmoid(go) * fast_tanh(c);

      // ---- publish h_{t+1} (tag t+1) immediately ----
      if (t + 1 < TSTEPS) {
        const unsigned hb = (unsigned)f2bf(hval);
        const unsigned pb = (unsigned)__shfl_xor((int)hb, 16, 64);
        if ((hi4 & 1) == 0) {
          const uint64_t val = (uint64_t)(uint32_t)(t + 1)
                             | ((uint64_t)(hb | (pb << 16)) << 32);
          __hip_atomic_store(h_buf + ((size_t)((t + 1) & 1) * NGROUPS + group) * HB_U64_PER_GROUP
                               + (size_t)bi * (HDIM / 2) + (mycol >> 1),
                             val, __ATOMIC_RELAXED, __HIP_MEMORY_SCOPE_AGENT);
        }
      }
      hout[u] = hval;   // static index (unrolled) -> stays in VGPRs
    }
    // ---- batched out flush (couples into a poll only once per 8 steps) ----
#pragma unroll
    for (int k = 0; k < 8; ++k)
      out[(size_t)(tb + k) * (BATCH * HDIM) + obase] = hout[k];
  }
}

extern "C" void kernel_launch(void* const* d_in, const int* in_sizes, int n_in,
                              void* d_out, int out_size, void* d_ws, size_t ws_size,
                              hipStream_t stream) {
  const float* x    = (const float*)d_in[0];
  const float* w_ih = (const float*)d_in[1];
  const float* w_hh = (const float*)d_in[2];
  const float* b_ih = (const float*)d_in[3];
  const float* b_hh = (const float*)d_in[4];
  float* out = (float*)d_out;

  char* ws = (char*)d_ws;
  float* bias = (float*)ws;                          // 8KB
  uint64_t* h_buf = (uint64_t*)(ws + 8192);          // 256KB tagged pairs

  lstm_init<<<8, 256, 0, stream>>>(b_ih, b_hh, bias, h_buf);
  lstm_persistent<<<NWG, 256, 0, stream>>>(x, w_ih, w_hh, bias, h_buf, out);
}